// Round 1
// baseline (149.137 us; speedup 1.0000x reference)
//
#include <hip/hip_runtime.h>

// Zero the whole output with vectorized float4 stores (grid-stride).
__global__ __launch_bounds__(256) void zero_f4(float4* __restrict__ out, int n4) {
    int i = blockIdx.x * blockDim.x + threadIdx.x;
    const int stride = gridDim.x * blockDim.x;
    float4 z = make_float4(0.f, 0.f, 0.f, 0.f);
    for (; i < n4; i += stride) out[i] = z;
}

// One block per (b,n) row. All 64 threads redundantly compute the row's
// keypoint gather + bilinear corner setup (uniform, trivial), then threads
// 0..35 write the 6x6 analytic blurred patch.
__global__ __launch_bounds__(64) void patch_k(const float* __restrict__ Xg,
                                              const float* __restrict__ kp,
                                              const float* __restrict__ gk,
                                              const int* __restrict__ pH,
                                              const int* __restrict__ pW,
                                              float* __restrict__ out,
                                              int N) {
    const int H = *pH, W = *pW;
    const int bn = blockIdx.x;
    const int b  = bn / N;

    const float* xrow = Xg + (size_t)bn * N;     // one-hot (or zero) row
    const float* kpb  = kp + (size_t)b * N * 2;  // keypoints for this batch

    // xy = Xg_row . keypoint_g ; mask = sum(Xg_row)
    float m = 0.f, sx = 0.f, sy = 0.f;
    for (int j = 0; j < N; ++j) {
        float w = xrow[j];
        m  += w;
        sx = fmaf(w, kpb[2 * j],     sx);
        sy = fmaf(w, kpb[2 * j + 1], sy);
    }
    if (m == 0.f) return;  // invalid row -> plane stays all-zero

    const float xf = sx * 0.0625f - 0.5f;   // / IM_FE_RATIO - 0.5
    const float yf = sy * 0.0625f - 0.5f;
    const float maxx = (float)(W - 1), maxy = (float)(H - 1);

    const float x0 = fminf(fmaxf(floorf(xf), 0.f), maxx);
    const float x1 = fminf(fmaxf(ceilf (xf), 0.f), maxx);
    const float y0 = fminf(fmaxf(floorf(yf), 0.f), maxy);
    const float y1 = fminf(fmaxf(ceilf (yf), 0.f), maxy);

    const float upx = xf - x0, lwx = 1.f - upx;
    const float upy = yf - y0, lwy = 1.f - upy;

    const int   xc[2] = { (int)x0, (int)x1 };
    const int   yc[2] = { (int)y0, (int)y1 };
    const float wx[2] = { lwx, upx };
    const float wy[2] = { lwy, upy };

    const int t = threadIdx.x;
    if (t >= 36) return;

    // Patch footprint: rows y0-2 .. y0+3 (covers y1+2 since y1<=y0+1), same in x.
    const int r = yc[0] - 2 + t / 6;
    const int c = xc[0] - 2 + t % 6;
    if (r < 0 || r >= H || c < 0 || c >= W) return;

    // out[r,c] = mask^2 * sum over 4 corners of coef * gk[(yc-r)+2, (xc-c)+2]
    float v = 0.f;
    #pragma unroll
    for (int cy = 0; cy < 2; ++cy) {
        const int dy = yc[cy] - r + 2;
        if (dy < 0 || dy > 4) continue;
        #pragma unroll
        for (int cx = 0; cx < 2; ++cx) {
            const int dx = xc[cx] - c + 2;
            if (dx < 0 || dx > 4) continue;
            v = fmaf(wy[cy] * wx[cx], gk[dy * 5 + dx], v);
        }
    }
    out[(size_t)bn * H * W + (size_t)r * W + c] = m * m * v;
}

extern "C" void kernel_launch(void* const* d_in, const int* in_sizes, int n_in,
                              void* d_out, int out_size, void* d_ws, size_t ws_size,
                              hipStream_t stream) {
    const float* Xg = (const float*)d_in[0];
    const float* kp = (const float*)d_in[1];
    const float* gk = (const float*)d_in[2];
    const int*   pH = (const int*)d_in[3];
    const int*   pW = (const int*)d_in[4];
    float* out = (float*)d_out;

    const int BN = in_sizes[1] / 2;            // B*N (keypoint_g is B*N*2)
    const int N  = in_sizes[0] / BN;           // Xg is B*N*N

    // 1) zero the full output (dominant cost: 134 MB of stores)
    const int n4 = out_size / 4;
    zero_f4<<<2048, 256, 0, stream>>>((float4*)out, n4);

    // 2) write the 6x6 analytic patches, one block per (b,n)
    patch_k<<<BN, 64, 0, stream>>>(Xg, kp, gk, pH, pW, out, N);
}

// Round 2
// 142.480 us; speedup vs baseline: 1.0467x; 1.0467x over previous
//
#include <hip/hip_runtime.h>

// One block (one wave) per (b,n) row. Lanes 0..31 cooperatively reduce the
// one-hot Xg row against keypoint_g (mask, x, y), wave-reduce via shuffles,
// then lanes 0..35 write the 6x6 analytic blurred patch:
//   out[r,c] = mask^2 * sum_{4 corners} coef * gk[(yc-r)+2, (xc-c)+2]
__global__ __launch_bounds__(64) void patch_k(const float* __restrict__ Xg,
                                              const float* __restrict__ kp,
                                              const float* __restrict__ gk,
                                              const int* __restrict__ pH,
                                              const int* __restrict__ pW,
                                              float* __restrict__ out,
                                              int N) {
    const int H = *pH, W = *pW;
    const int bn = blockIdx.x;
    const int b  = bn / N;
    const int t  = threadIdx.x;

    const float* xrow = Xg + (size_t)bn * N;     // one-hot (or zero) row
    const float* kpb  = kp + (size_t)b * N * 2;  // keypoints for this batch

    // Lane-parallel reduction over N (N<=64 assumed; here N=32).
    float m = 0.f, sx = 0.f, sy = 0.f;
    for (int j = t; j < N; j += 64) {
        float w = xrow[j];
        m  += w;
        sx = fmaf(w, kpb[2 * j],     sx);
        sy = fmaf(w, kpb[2 * j + 1], sy);
    }
    #pragma unroll
    for (int off = 32; off > 0; off >>= 1) {
        m  += __shfl_xor(m,  off, 64);
        sx += __shfl_xor(sx, off, 64);
        sy += __shfl_xor(sy, off, 64);
    }
    if (m == 0.f) return;  // invalid row -> plane stays all-zero

    const float xf = sx * 0.0625f - 0.5f;   // / IM_FE_RATIO - 0.5
    const float yf = sy * 0.0625f - 0.5f;
    const float maxx = (float)(W - 1), maxy = (float)(H - 1);

    const float x0 = fminf(fmaxf(floorf(xf), 0.f), maxx);
    const float x1 = fminf(fmaxf(ceilf (xf), 0.f), maxx);
    const float y0 = fminf(fmaxf(floorf(yf), 0.f), maxy);
    const float y1 = fminf(fmaxf(ceilf (yf), 0.f), maxy);

    const float upx = xf - x0, lwx = 1.f - upx;
    const float upy = yf - y0, lwy = 1.f - upy;

    const int   xc[2] = { (int)x0, (int)x1 };
    const int   yc[2] = { (int)y0, (int)y1 };
    const float wx[2] = { lwx, upx };
    const float wy[2] = { lwy, upy };

    if (t >= 36) return;

    // Patch footprint: rows y0-2 .. y0+3 (covers y1+2 since y1<=y0+1), same in x.
    const int r = yc[0] - 2 + t / 6;
    const int c = xc[0] - 2 + t % 6;
    if (r < 0 || r >= H || c < 0 || c >= W) return;

    float v = 0.f;
    #pragma unroll
    for (int cy = 0; cy < 2; ++cy) {
        const int dy = yc[cy] - r + 2;
        if (dy < 0 || dy > 4) continue;
        #pragma unroll
        for (int cx = 0; cx < 2; ++cx) {
            const int dx = xc[cx] - c + 2;
            if (dx < 0 || dx > 4) continue;
            v = fmaf(wy[cy] * wx[cx], gk[dy * 5 + dx], v);
        }
    }
    out[(size_t)bn * H * W + (size_t)r * W + c] = m * m * v;
}

extern "C" void kernel_launch(void* const* d_in, const int* in_sizes, int n_in,
                              void* d_out, int out_size, void* d_ws, size_t ws_size,
                              hipStream_t stream) {
    const float* Xg = (const float*)d_in[0];
    const float* kp = (const float*)d_in[1];
    const float* gk = (const float*)d_in[2];
    const int*   pH = (const int*)d_in[3];
    const int*   pW = (const int*)d_in[4];
    float* out = (float*)d_out;

    const int BN = in_sizes[1] / 2;            // B*N (keypoint_g is B*N*2)
    const int N  = in_sizes[0] / BN;           // Xg is B*N*N

    // 1) zero the full output via the runtime's optimized fill path
    //    (measured 6.58 TB/s on this chip; graph-capturable as a memset node)
    hipMemsetAsync(out, 0, (size_t)out_size * sizeof(float), stream);

    // 2) write the 6x6 analytic patches, one wave per (b,n)
    patch_k<<<BN, 64, 0, stream>>>(Xg, kp, gk, pH, pW, out, N);
}